// Round 18
// baseline (217.091 us; speedup 1.0000x reference)
//
#include <hip/hip_runtime.h>
#include <hip/hip_bf16.h>
#include <stdint.h>

#define D 128

typedef __attribute__((ext_vector_type(8))) short short8;
typedef __attribute__((ext_vector_type(4))) float f32x4;

__device__ inline unsigned short f2bf(float f) {
    union { float f; uint32_t u; } v; v.f = f;
    uint32_t u = v.u;
    uint32_t r = u + 0x7FFFu + ((u >> 16) & 1u);   // RNE
    return (unsigned short)(r >> 16);
}

__device__ inline float bf2f(uint32_t ubf) {
    union { uint32_t u; float f; } v; v.u = ubf << 16; return v.f;
}

// epilogue LDS swizzle
__device__ inline int eswz(int row) {
    return ((row & 3) << 5) | (((row >> 2) & 1) << 4);
}

// ---- fused: prep weights transposed PLAIN layout (blocks 0..191) + zero cnt
__global__ void prep_zero(const float* __restrict__ W0, const float* __restrict__ W1,
                          const float* __restrict__ W2, unsigned short* __restrict__ Wt,
                          int* __restrict__ cnt, int nz) {
    int b = blockIdx.x;
    if (b < 192) {
        int idx = b * 256 + threadIdx.x;   // < 3*D*D = 49152
        int w = idx / (D * D);
        int rem = idx - w * D * D;
        int c = rem / D, k = rem - c * D;
        const float* W = (w == 0) ? W0 : ((w == 1) ? W1 : W2);
        Wt[idx] = f2bf(W[k * D + c]);      // Wt[w][c][k]
    } else {
        int i = (b - 192) * 256 + threadIdx.x;
        if (i < nz) cnt[i] = 0;
    }
}

// ---- fused GEMM (+histogram-with-rank in trailing blocks)
// B fragments read DIRECTLY from global (3 tiles = 96KB, L1/L2-resident):
// no B staging, no staging barriers. LDS = 16KB epilogue buffer only.
__launch_bounds__(256, 3)
__global__ void gemm_hist(const float* __restrict__ x, const unsigned short* __restrict__ Wt,
                          const float* __restrict__ bln, float* __restrict__ out0,
                          unsigned short* __restrict__ h1, unsigned short* __restrict__ h2,
                          int N, int nGemm,
                          const int* __restrict__ ei1, const int* __restrict__ ei2,
                          int E1, int E2, int* __restrict__ cnt, int* __restrict__ epos,
                          int N1) {
    __shared__ char lA[64 * 256];    // 16KB epilogue bf16 staging
    const int b = blockIdx.x;
    const int tid = threadIdx.x;

    if (b >= nGemm) {                // histogram tail blocks: count + store rank
        int g = (b - nGemm) * 256 + tid;
        if (g < E1) {
            epos[g] = atomicAdd(&cnt[ei1[E1 + g]], 1);
        } else if (g < E1 + E2) {
            int e = g - E1;
            epos[g] = atomicAdd(&cnt[N1 + ei2[E2 + e]], 1);
        }
        return;
    }

    const int r0 = b * 64;
    const int wv = tid >> 6, lane = tid & 63;
    const int lr = lane & 15, lk = lane >> 4;

    // A fragments directly from global (f32 -> bf16 in regs)
    short8 afr[4];
    {
        int arow = r0 + wv * 16 + lr;
        if (arow < N) {
            const float* xr = x + (size_t)arow * D;
#pragma unroll
            for (int ks = 0; ks < 4; ++ks) {
                int c0 = ks * 32 + lk * 8;
                float4 va = *(const float4*)(xr + c0);
                float4 vb = *(const float4*)(xr + c0 + 4);
                short8 f;
                f[0] = (short)f2bf(va.x); f[1] = (short)f2bf(va.y);
                f[2] = (short)f2bf(va.z); f[3] = (short)f2bf(va.w);
                f[4] = (short)f2bf(vb.x); f[5] = (short)f2bf(vb.y);
                f[6] = (short)f2bf(vb.z); f[7] = (short)f2bf(vb.w);
                afr[ks] = f;
            }
        } else {
#pragma unroll
            for (int ks = 0; ks < 4; ++ks) afr[ks] = (short8)0;
        }
    }

    f32x4 acc[8];

    // MFMA for one widx: B fragments from global (L1/L2-resident)
    auto mfma_tile = [&](int widx) {
        const unsigned short* Wb = Wt + widx * D * D;
#pragma unroll
        for (int c = 0; c < 8; ++c) acc[c] = (f32x4)(0.f);
#pragma unroll
        for (int ks = 0; ks < 4; ++ks) {
            short8 bfr[8];
#pragma unroll
            for (int c = 0; c < 8; ++c)
                bfr[c] = *(const short8*)(Wb + (c * 16 + lr) * D + ks * 32 + lk * 8);
#pragma unroll
            for (int c = 0; c < 8; ++c)
                acc[c] = __builtin_amdgcn_mfma_f32_16x16x32_bf16(afr[ks], bfr[c], acc[c], 0, 0, 0);
        }
    };

    // bf16 epilogue via LDS for full-line h writes
    auto stage_h = [&](unsigned short* h, bool preBar) {
        if (preBar) __syncthreads();   // prior lA readers done
#pragma unroll
        for (int c = 0; c < 8; ++c) {
            int col = c * 16 + lr;
#pragma unroll
            for (int i = 0; i < 4; ++i) {
                int row_l = wv * 16 + lk * 4 + i;
                int byt = (row_l * 256 + col * 2) ^ eswz(row_l);
                *(unsigned short*)(lA + byt) = f2bf(acc[c][i]);
            }
        }
        __syncthreads();
#pragma unroll
        for (int i = 0; i < 4; ++i) {
            int idx = i * 256 + tid;
            int lin = idx * 16;
            int row_l = lin >> 8;
            int rb = lin ^ eswz(row_l);
            uint4 v = *(const uint4*)(lA + rb);
            int grow = r0 + row_l;
            if (grow < N)
                *(uint4*)((char*)h + (size_t)grow * 256 + (lin & 255)) = v;
        }
    };

    // widx = 0: out0 = x@Wln + bln (f32, direct stores, no barrier)
    mfma_tile(0);
    {
        float blnv[8];
#pragma unroll
        for (int c = 0; c < 8; ++c) blnv[c] = bln[c * 16 + lr];
#pragma unroll
        for (int i = 0; i < 4; ++i) {
            int grow = r0 + wv * 16 + lk * 4 + i;
            if (grow < N) {
                float* orow = out0 + (size_t)grow * D;
#pragma unroll
                for (int c = 0; c < 8; ++c)
                    orow[c * 16 + lr] = acc[c][i] + blnv[c];
            }
        }
    }

    // widx = 1 -> h1 ; widx = 2 -> h2
    mfma_tile(1);
    stage_h(h1, false);
    mfma_tile(2);
    stage_h(h2, true);
}

// ---- exclusive scan, 1024 elems/block (256 thr x 4); block sums left un-added
__global__ void scan1_k(const int* __restrict__ cnt, int* __restrict__ excl,
                        int* __restrict__ bsum, int n) {
    __shared__ int s[256];
    int t = threadIdx.x;
    int base = blockIdx.x * 1024 + t * 4;
    int v0 = 0, v1 = 0, v2 = 0, v3 = 0;
    if (base + 3 < n) {
        int4 q = *(const int4*)(cnt + base);
        v0 = q.x; v1 = q.y; v2 = q.z; v3 = q.w;
    } else {
        if (base < n) v0 = cnt[base];
        if (base + 1 < n) v1 = cnt[base + 1];
        if (base + 2 < n) v2 = cnt[base + 2];
    }
    int sum = v0 + v1 + v2 + v3;
    s[t] = sum; __syncthreads();
    for (int off = 1; off < 256; off <<= 1) {
        int x = (t >= off) ? s[t - off] : 0;
        __syncthreads();
        s[t] += x;
        __syncthreads();
    }
    if (t == 255) bsum[blockIdx.x] = s[255];
    int run = s[t] - sum;
    if (base < n) excl[base] = run;
    if (base + 1 < n) excl[base + 1] = run + v0;
    if (base + 2 < n) excl[base + 2] = run + v0 + v1;
    if (base + 3 < n) excl[base + 3] = run + v0 + v1 + v2;
}

__global__ void scan2_k(int* __restrict__ bsum, int nb) {
    __shared__ int s[256];
    int t = threadIdx.x;
    int v = (t < nb) ? bsum[t] : 0;
    s[t] = v; __syncthreads();
    for (int off = 1; off < 256; off <<= 1) {
        int x = (t >= off) ? s[t - off] : 0;
        __syncthreads();
        s[t] += x;
        __syncthreads();
    }
    if (t < nb) bsum[t] = s[t] - v;
}

// ---- fill slots (no atomics): slot[rowptr[bin]+bsum[bin>>10]+epos[g]] = {src, w}
__global__ void fill_k(const int* __restrict__ ei1, const float* __restrict__ ew1,
                       const int* __restrict__ ei2, const float* __restrict__ ew2,
                       int E1, int E2, const int* __restrict__ rowptr,
                       const int* __restrict__ bsum, const int* __restrict__ epos,
                       uint2* __restrict__ slots, int N1) {
    int g = blockIdx.x * blockDim.x + threadIdx.x;
    int src, bin; float w;
    if (g < E1) {
        src = ei1[g]; bin = ei1[E1 + g]; w = ew1[g];
    } else if (g < E1 + E2) {
        int e = g - E1;
        src = ei2[e]; bin = N1 + ei2[E2 + e]; w = ew2[e];
    } else return;
    uint2 v; v.x = (unsigned)src; v.y = __float_as_uint(w);
    slots[rowptr[bin] + bsum[bin >> 10] + epos[g]] = v;
}

// ---- gather: one wave per (branch,node); quarter-wave edge pairing.
__launch_bounds__(256)
__global__ void gather_k(const uint2* __restrict__ slots, const int* __restrict__ rowptr,
                         const int* __restrict__ bsum,
                         const unsigned short* __restrict__ h1, const unsigned short* __restrict__ h2,
                         const float* __restrict__ b1, const float* __restrict__ b2,
                         float* __restrict__ out12, int N, int N1) {
    int wave = (blockIdx.x * 256 + threadIdx.x) >> 6;   // [0, 2N)
    int lane = threadIdx.x & 63;
    if (wave >= 2 * N) return;
    int q = lane >> 4, sl = lane & 15;
    int br = wave >= N;
    int node = wave - br * N;
    int rp = br * N1 + node;
    int beg = rowptr[rp] + bsum[rp >> 10];
    int end = rowptr[rp + 1] + bsum[(rp + 1) >> 10];
    const unsigned short* h = br ? h2 : h1;
    const float* bias = br ? b2 : b1;

    float a[8];
#pragma unroll
    for (int i = 0; i < 8; ++i) a[i] = 0.f;

    int j = beg + q;
    for (; j + 4 < end; j += 8) {
        uint2 s0 = slots[j], s1 = slots[j + 4];
        uint4 p0 = *(const uint4*)(h + (size_t)s0.x * D + sl * 8);
        uint4 p1 = *(const uint4*)(h + (size_t)s1.x * D + sl * 8);
        float w0 = __uint_as_float(s0.y), w1 = __uint_as_float(s1.y);
        a[0] += w0 * bf2f(p0.x & 0xFFFFu) + w1 * bf2f(p1.x & 0xFFFFu);
        a[1] += w0 * bf2f(p0.x >> 16)     + w1 * bf2f(p1.x >> 16);
        a[2] += w0 * bf2f(p0.y & 0xFFFFu) + w1 * bf2f(p1.y & 0xFFFFu);
        a[3] += w0 * bf2f(p0.y >> 16)     + w1 * bf2f(p1.y >> 16);
        a[4] += w0 * bf2f(p0.z & 0xFFFFu) + w1 * bf2f(p1.z & 0xFFFFu);
        a[5] += w0 * bf2f(p0.z >> 16)     + w1 * bf2f(p1.z >> 16);
        a[6] += w0 * bf2f(p0.w & 0xFFFFu) + w1 * bf2f(p1.w & 0xFFFFu);
        a[7] += w0 * bf2f(p0.w >> 16)     + w1 * bf2f(p1.w >> 16);
    }
    if (j < end) {
        uint2 s0 = slots[j];
        uint4 p0 = *(const uint4*)(h + (size_t)s0.x * D + sl * 8);
        float w0 = __uint_as_float(s0.y);
        a[0] += w0 * bf2f(p0.x & 0xFFFFu);
        a[1] += w0 * bf2f(p0.x >> 16);
        a[2] += w0 * bf2f(p0.y & 0xFFFFu);
        a[3] += w0 * bf2f(p0.y >> 16);
        a[4] += w0 * bf2f(p0.z & 0xFFFFu);
        a[5] += w0 * bf2f(p0.z >> 16);
        a[6] += w0 * bf2f(p0.w & 0xFFFFu);
        a[7] += w0 * bf2f(p0.w >> 16);
    }
#pragma unroll
    for (int i = 0; i < 8; ++i) {
        a[i] += __shfl_xor(a[i], 16);
        a[i] += __shfl_xor(a[i], 32);
    }
    if (q == 0) {
        float4 b0 = *(const float4*)(bias + sl * 8);
        float4 b1v = *(const float4*)(bias + sl * 8 + 4);
        f32x4 o0, o1;
        o0[0] = a[0] + b0.x;  o0[1] = a[1] + b0.y;  o0[2] = a[2] + b0.z;  o0[3] = a[3] + b0.w;
        o1[0] = a[4] + b1v.x; o1[1] = a[5] + b1v.y; o1[2] = a[6] + b1v.z; o1[3] = a[7] + b1v.w;
        float* dst = out12 + (size_t)wave * D + sl * 8;
        __builtin_nontemporal_store(o0, (f32x4*)dst);
        __builtin_nontemporal_store(o1, (f32x4*)(dst + 4));
    }
}

extern "C" void kernel_launch(void* const* d_in, const int* in_sizes, int n_in,
                              void* d_out, int out_size, void* d_ws, size_t ws_size,
                              hipStream_t stream) {
    const float* x   = (const float*)d_in[0];
    const int*   ei1 = (const int*)d_in[1];
    const float* ew1 = (const float*)d_in[2];
    const int*   ei2 = (const int*)d_in[3];
    const float* ew2 = (const float*)d_in[4];
    const float* Wln = (const float*)d_in[5];
    const float* bln = (const float*)d_in[6];
    const float* W1  = (const float*)d_in[7];
    const float* b1  = (const float*)d_in[8];
    const float* W2  = (const float*)d_in[9];
    const float* b2  = (const float*)d_in[10];

    const int N  = in_sizes[0] / D;
    const int E1 = in_sizes[2];
    const int E2 = in_sizes[4];
    const int N1 = N + 1;
    const int n  = 2 * N1;                 // concatenated bins
    const int nb = (n + 1023) / 1024;      // scan blocks (<=256)

    float* out0  = (float*)d_out;
    float* out12 = out0 + (size_t)N * D;

    char* ws = (char*)d_ws;
    size_t off = 0;
    auto alloc = [&](size_t bytes) { char* p = ws + off; off += (bytes + 63) & ~(size_t)63; return p; };
    unsigned short* h1     = (unsigned short*)alloc((size_t)N * D * 2);
    unsigned short* h2     = (unsigned short*)alloc((size_t)N * D * 2);
    unsigned short* Wt     = (unsigned short*)alloc(3 * D * D * 2);
    int*            cnt    = (int*)alloc((size_t)n * 4);
    int*            rowptr = (int*)alloc((size_t)n * 4);
    int*            bsum   = (int*)alloc(1024);
    int*            epos   = (int*)alloc((size_t)(E1 + E2) * 4);
    uint2*          slots  = (uint2*)alloc((size_t)(E1 + E2) * 8);

    const int nGemm = (N + 63) / 64;
    const int nHist = (E1 + E2 + 255) / 256;
    const int nZero = (n + 255) / 256;

    prep_zero<<<192 + nZero, 256, 0, stream>>>(Wln, W1, W2, Wt, cnt, n);
    gemm_hist<<<nGemm + nHist, 256, 0, stream>>>(x, Wt, bln, out0, h1, h2, N, nGemm,
                                                 ei1, ei2, E1, E2, cnt, epos, N1);
    scan1_k<<<nb, 256, 0, stream>>>(cnt, rowptr, bsum, n);
    scan2_k<<<1, 256, 0, stream>>>(bsum, nb);
    fill_k<<<(E1 + E2 + 255) / 256, 256, 0, stream>>>(ei1, ew1, ei2, ew2, E1, E2,
                                                      rowptr, bsum, epos, slots, N1);
    gather_k<<<(2 * N + 3) / 4, 256, 0, stream>>>(slots, rowptr, bsum, h1, h2, b1, b2,
                                                  out12, N, N1);
}

// Round 19
// 205.933 us; speedup vs baseline: 1.0542x; 1.0542x over previous
//
#include <hip/hip_runtime.h>
#include <hip/hip_bf16.h>
#include <stdint.h>

#define D 128

typedef __attribute__((ext_vector_type(8))) short short8;
typedef __attribute__((ext_vector_type(4))) float f32x4;

__device__ inline unsigned short f2bf(float f) {
    union { float f; uint32_t u; } v; v.f = f;
    uint32_t u = v.u;
    uint32_t r = u + 0x7FFFu + ((u >> 16) & 1u);   // RNE
    return (unsigned short)(r >> 16);
}

__device__ inline float bf2f(uint32_t ubf) {
    union { uint32_t u; float f; } v; v.u = ubf << 16; return v.f;
}

// epilogue LDS swizzle: rows 1-apart AND 4-apart land in distinct 16B slots
__device__ inline int eswz(int row) {
    return ((row & 3) << 5) | (((row >> 2) & 1) << 4);
}

// ---- fused: prep weights pre-swizzled (blocks 0..191) + zero cnt (blocks 192..)
__global__ void prep_zero(const float* __restrict__ W0, const float* __restrict__ W1,
                          const float* __restrict__ W2, unsigned short* __restrict__ Wt,
                          int* __restrict__ cnt, int nz) {
    int b = blockIdx.x;
    if (b < 192) {
        int idx = b * 256 + threadIdx.x;   // < 3*D*D = 49152
        int w = idx / (D * D);
        int rem = idx - w * D * D;
        int c = rem / D, k = rem - c * D;
        const float* W = (w == 0) ? W0 : ((w == 1) ? W1 : W2);
        int byte = ((c << 8) | (k << 1)) ^ ((c & 7) << 4);
        Wt[w * (D * D) + (byte >> 1)] = f2bf(W[k * D + c]);
    } else {
        int i = (b - 192) * 256 + threadIdx.x;
        if (i < nz) cnt[i] = 0;
    }
}

// ---- fused GEMM (+histogram-with-rank in trailing blocks)  [R15 shape]
__launch_bounds__(256, 3)
__global__ void gemm_hist(const float* __restrict__ x, const unsigned short* __restrict__ Wt,
                          const float* __restrict__ bln, float* __restrict__ out0,
                          unsigned short* __restrict__ h1, unsigned short* __restrict__ h2,
                          int N, int nGemm,
                          const int* __restrict__ ei1, const int* __restrict__ ei2,
                          int E1, int E2, int* __restrict__ cnt, int* __restrict__ epos,
                          int N1) {
    __shared__ char lA[64 * 256];    // epilogue bf16 staging (16KB)
    __shared__ char lB[D * 256];     // B stage, swizzled layout (32KB)
    const int b = blockIdx.x;
    const int tid = threadIdx.x;

    if (b >= nGemm) {                // histogram tail blocks: count + store rank
        int g = (b - nGemm) * 256 + tid;
        if (g < E1) {
            epos[g] = atomicAdd(&cnt[ei1[E1 + g]], 1);
        } else if (g < E1 + E2) {
            int e = g - E1;
            epos[g] = atomicAdd(&cnt[N1 + ei2[E2 + e]], 1);
        }
        return;
    }

    const int r0 = b * 64;
    const int wv = tid >> 6, lane = tid & 63;
    const int lr = lane & 15, lk = lane >> 4;

    // A fragments directly from global (f32 -> bf16 in regs)
    short8 afr[4];
    {
        int arow = r0 + wv * 16 + lr;
        if (arow < N) {
            const float* xr = x + (size_t)arow * D;
#pragma unroll
            for (int ks = 0; ks < 4; ++ks) {
                int c0 = ks * 32 + lk * 8;
                float4 va = *(const float4*)(xr + c0);
                float4 vb = *(const float4*)(xr + c0 + 4);
                short8 f;
                f[0] = (short)f2bf(va.x); f[1] = (short)f2bf(va.y);
                f[2] = (short)f2bf(va.z); f[3] = (short)f2bf(va.w);
                f[4] = (short)f2bf(vb.x); f[5] = (short)f2bf(vb.y);
                f[6] = (short)f2bf(vb.z); f[7] = (short)f2bf(vb.w);
                afr[ks] = f;
            }
        } else {
#pragma unroll
            for (int ks = 0; ks < 4; ++ks) afr[ks] = (short8)0;
        }
    }
    float blnv[8];
#pragma unroll
    for (int c = 0; c < 8; ++c) blnv[c] = bln[c * 16 + lr];

    for (int widx = 0; widx < 3; ++widx) {
        __syncthreads();   // prev iteration's lB MFMA reads + lA epilogue reads done
        // B tile: pre-swizzled global -> linear LDS (transient regs, 16B/thread x8)
        {
            const uint4* src = (const uint4*)(Wt + widx * D * D);
            uint4* dst = (uint4*)lB;
#pragma unroll
            for (int i = 0; i < 8; ++i) {
                int idx16 = i * 256 + tid;
                dst[idx16] = src[idx16];
            }
        }
        __syncthreads();

        f32x4 acc[8];
#pragma unroll
        for (int c = 0; c < 8; ++c) acc[c] = (f32x4)(0.f);

#pragma unroll
        for (int ks = 0; ks < 4; ++ks) {
            short8 bfr[8];
#pragma unroll
            for (int c = 0; c < 8; ++c) {
                int row = c * 16 + lr;
                int byte = row * 256 + ks * 64 + lk * 16;
                byte ^= (row & 7) << 4;
                bfr[c] = *(const short8*)(lB + byte);
            }
#pragma unroll
            for (int c = 0; c < 8; ++c)
                acc[c] = __builtin_amdgcn_mfma_f32_16x16x32_bf16(afr[ks], bfr[c], acc[c], 0, 0, 0);
        }

        // C/D mapping: col=lane&15, row=(lane>>4)*4+i
        if (widx == 0) {
            // i-outer/c-inner: one row's 8 col-chunks issue back-to-back
#pragma unroll
            for (int i = 0; i < 4; ++i) {
                int grow = r0 + wv * 16 + lk * 4 + i;
                if (grow < N) {
                    float* orow = out0 + (size_t)grow * D;
#pragma unroll
                    for (int c = 0; c < 8; ++c)
                        orow[c * 16 + lr] = acc[c][i] + blnv[c];
                }
            }
        } else {
#pragma unroll
            for (int c = 0; c < 8; ++c) {
                int col = c * 16 + lr;
#pragma unroll
                for (int i = 0; i < 4; ++i) {
                    int row_l = wv * 16 + lk * 4 + i;
                    int byt = (row_l * 256 + col * 2) ^ eswz(row_l);
                    *(unsigned short*)(lA + byt) = f2bf(acc[c][i]);
                }
            }
            __syncthreads();
            unsigned short* h = (widx == 1) ? h1 : h2;
#pragma unroll
            for (int i = 0; i < 4; ++i) {
                int idx = i * 256 + tid;
                int lin = idx * 16;
                int row_l = lin >> 8;
                int rb = lin ^ eswz(row_l);
                uint4 v = *(const uint4*)(lA + rb);
                int grow = r0 + row_l;
                if (grow < N)
                    *(uint4*)((char*)h + (size_t)grow * 256 + (lin & 255)) = v;
            }
        }
    }
}

// ---- exclusive scan, 1024 elems/block (256 thr x 4); block sums left un-added
__global__ void scan1_k(const int* __restrict__ cnt, int* __restrict__ excl,
                        int* __restrict__ bsum, int n) {
    __shared__ int s[256];
    int t = threadIdx.x;
    int base = blockIdx.x * 1024 + t * 4;
    int v0 = 0, v1 = 0, v2 = 0, v3 = 0;
    if (base + 3 < n) {
        int4 q = *(const int4*)(cnt + base);
        v0 = q.x; v1 = q.y; v2 = q.z; v3 = q.w;
    } else {
        if (base < n) v0 = cnt[base];
        if (base + 1 < n) v1 = cnt[base + 1];
        if (base + 2 < n) v2 = cnt[base + 2];
    }
    int sum = v0 + v1 + v2 + v3;
    s[t] = sum; __syncthreads();
    for (int off = 1; off < 256; off <<= 1) {
        int x = (t >= off) ? s[t - off] : 0;
        __syncthreads();
        s[t] += x;
        __syncthreads();
    }
    if (t == 255) bsum[blockIdx.x] = s[255];
    int run = s[t] - sum;
    if (base < n) excl[base] = run;
    if (base + 1 < n) excl[base + 1] = run + v0;
    if (base + 2 < n) excl[base + 2] = run + v0 + v1;
    if (base + 3 < n) excl[base + 3] = run + v0 + v1 + v2;
}

// ---- fill slots (no atomics); bsum exclusive-scanned in-block
__global__ void fill_k(const int* __restrict__ ei1, const float* __restrict__ ew1,
                       const int* __restrict__ ei2, const float* __restrict__ ew2,
                       int E1, int E2, const int* __restrict__ rowptr,
                       const int* __restrict__ bsum, int nb,
                       const int* __restrict__ epos,
                       uint2* __restrict__ slots, int N1) {
    __shared__ int sb[256];
    int t = threadIdx.x;
    {
        int v = (t < nb) ? bsum[t] : 0;
        sb[t] = v; __syncthreads();
        for (int off = 1; off < 256; off <<= 1) {
            int x = (t >= off) ? sb[t - off] : 0;
            __syncthreads();
            sb[t] += x;
            __syncthreads();
        }
        int excl = sb[t] - v;
        __syncthreads();
        sb[t] = excl;
        __syncthreads();
    }
    int g = blockIdx.x * blockDim.x + t;
    int src, bin; float w;
    if (g < E1) {
        src = ei1[g]; bin = ei1[E1 + g]; w = ew1[g];
    } else if (g < E1 + E2) {
        int e = g - E1;
        src = ei2[e]; bin = N1 + ei2[E2 + e]; w = ew2[e];
    } else return;
    uint2 v; v.x = (unsigned)src; v.y = __float_as_uint(w);
    slots[rowptr[bin] + sb[bin >> 10] + epos[g]] = v;
}

// ---- gather: one wave per (branch,node); quarter-wave edge pairing.
// bsum exclusive-scanned in-block.
__launch_bounds__(256)
__global__ void gather_k(const uint2* __restrict__ slots, const int* __restrict__ rowptr,
                         const int* __restrict__ bsum, int nb,
                         const unsigned short* __restrict__ h1, const unsigned short* __restrict__ h2,
                         const float* __restrict__ b1, const float* __restrict__ b2,
                         float* __restrict__ out12, int N, int N1) {
    __shared__ int sb[256];
    int t = threadIdx.x;
    {
        int v = (t < nb) ? bsum[t] : 0;
        sb[t] = v; __syncthreads();
        for (int off = 1; off < 256; off <<= 1) {
            int x = (t >= off) ? sb[t - off] : 0;
            __syncthreads();
            sb[t] += x;
            __syncthreads();
        }
        int excl = sb[t] - v;
        __syncthreads();
        sb[t] = excl;
        __syncthreads();
    }
    int wave = (blockIdx.x * 256 + t) >> 6;   // [0, 2N)
    int lane = t & 63;
    if (wave >= 2 * N) return;
    int q = lane >> 4, sl = lane & 15;
    int br = wave >= N;
    int node = wave - br * N;
    int rp = br * N1 + node;
    int beg = rowptr[rp] + sb[rp >> 10];
    int end = rowptr[rp + 1] + sb[(rp + 1) >> 10];
    const unsigned short* h = br ? h2 : h1;
    const float* bias = br ? b2 : b1;

    float a[8];
#pragma unroll
    for (int i = 0; i < 8; ++i) a[i] = 0.f;

    int j = beg + q;
    for (; j + 4 < end; j += 8) {
        uint2 s0 = slots[j], s1 = slots[j + 4];
        uint4 p0 = *(const uint4*)(h + (size_t)s0.x * D + sl * 8);
        uint4 p1 = *(const uint4*)(h + (size_t)s1.x * D + sl * 8);
        float w0 = __uint_as_float(s0.y), w1 = __uint_as_float(s1.y);
        a[0] += w0 * bf2f(p0.x & 0xFFFFu) + w1 * bf2f(p1.x & 0xFFFFu);
        a[1] += w0 * bf2f(p0.x >> 16)     + w1 * bf2f(p1.x >> 16);
        a[2] += w0 * bf2f(p0.y & 0xFFFFu) + w1 * bf2f(p1.y & 0xFFFFu);
        a[3] += w0 * bf2f(p0.y >> 16)     + w1 * bf2f(p1.y >> 16);
        a[4] += w0 * bf2f(p0.z & 0xFFFFu) + w1 * bf2f(p1.z & 0xFFFFu);
        a[5] += w0 * bf2f(p0.z >> 16)     + w1 * bf2f(p1.z >> 16);
        a[6] += w0 * bf2f(p0.w & 0xFFFFu) + w1 * bf2f(p1.w & 0xFFFFu);
        a[7] += w0 * bf2f(p0.w >> 16)     + w1 * bf2f(p1.w >> 16);
    }
    if (j < end) {
        uint2 s0 = slots[j];
        uint4 p0 = *(const uint4*)(h + (size_t)s0.x * D + sl * 8);
        float w0 = __uint_as_float(s0.y);
        a[0] += w0 * bf2f(p0.x & 0xFFFFu);
        a[1] += w0 * bf2f(p0.x >> 16);
        a[2] += w0 * bf2f(p0.y & 0xFFFFu);
        a[3] += w0 * bf2f(p0.y >> 16);
        a[4] += w0 * bf2f(p0.z & 0xFFFFu);
        a[5] += w0 * bf2f(p0.z >> 16);
        a[6] += w0 * bf2f(p0.w & 0xFFFFu);
        a[7] += w0 * bf2f(p0.w >> 16);
    }
#pragma unroll
    for (int i = 0; i < 8; ++i) {
        a[i] += __shfl_xor(a[i], 16);
        a[i] += __shfl_xor(a[i], 32);
    }
    if (q == 0) {
        float4 b0 = *(const float4*)(bias + sl * 8);
        float4 b1v = *(const float4*)(bias + sl * 8 + 4);
        f32x4 o0, o1;
        o0[0] = a[0] + b0.x;  o0[1] = a[1] + b0.y;  o0[2] = a[2] + b0.z;  o0[3] = a[3] + b0.w;
        o1[0] = a[4] + b1v.x; o1[1] = a[5] + b1v.y; o1[2] = a[6] + b1v.z; o1[3] = a[7] + b1v.w;
        float* dst = out12 + (size_t)wave * D + sl * 8;
        __builtin_nontemporal_store(o0, (f32x4*)dst);
        __builtin_nontemporal_store(o1, (f32x4*)(dst + 4));
    }
}

extern "C" void kernel_launch(void* const* d_in, const int* in_sizes, int n_in,
                              void* d_out, int out_size, void* d_ws, size_t ws_size,
                              hipStream_t stream) {
    const float* x   = (const float*)d_in[0];
    const int*   ei1 = (const int*)d_in[1];
    const float* ew1 = (const float*)d_in[2];
    const int*   ei2 = (const int*)d_in[3];
    const float* ew2 = (const float*)d_in[4];
    const float* Wln = (const float*)d_in[5];
    const float* bln = (const float*)d_in[6];
    const float* W1  = (const float*)d_in[7];
    const float* b1  = (const float*)d_in[8];
    const float* W2  = (const float*)d_in[9];
    const float* b2  = (const float*)d_in[10];

    const int N  = in_sizes[0] / D;
    const int E1 = in_sizes[2];
    const int E2 = in_sizes[4];
    const int N1 = N + 1;
    const int n  = 2 * N1;                 // concatenated bins
    const int nb = (n + 1023) / 1024;      // scan blocks (<=256)

    float* out0  = (float*)d_out;
    float* out12 = out0 + (size_t)N * D;

    char* ws = (char*)d_ws;
    size_t off = 0;
    auto alloc = [&](size_t bytes) { char* p = ws + off; off += (bytes + 63) & ~(size_t)63; return p; };
    unsigned short* h1     = (unsigned short*)alloc((size_t)N * D * 2);
    unsigned short* h2     = (unsigned short*)alloc((size_t)N * D * 2);
    unsigned short* Wt     = (unsigned short*)alloc(3 * D * D * 2);
    int*            cnt    = (int*)alloc((size_t)n * 4);
    int*            rowptr = (int*)alloc((size_t)n * 4);
    int*            bsum   = (int*)alloc(1024);
    int*            epos   = (int*)alloc((size_t)(E1 + E2) * 4);
    uint2*          slots  = (uint2*)alloc((size_t)(E1 + E2) * 8);

    const int nGemm = (N + 63) / 64;
    const int nHist = (E1 + E2 + 255) / 256;
    const int nZero = (n + 255) / 256;

    prep_zero<<<192 + nZero, 256, 0, stream>>>(Wln, W1, W2, Wt, cnt, n);
    gemm_hist<<<nGemm + nHist, 256, 0, stream>>>(x, Wt, bln, out0, h1, h2, N, nGemm,
                                                 ei1, ei2, E1, E2, cnt, epos, N1);
    scan1_k<<<nb, 256, 0, stream>>>(cnt, rowptr, bsum, n);
    fill_k<<<(E1 + E2 + 255) / 256, 256, 0, stream>>>(ei1, ew1, ei2, ew2, E1, E2,
                                                      rowptr, bsum, nb, epos, slots, N1);
    gather_k<<<(2 * N + 3) / 4, 256, 0, stream>>>(slots, rowptr, bsum, nb, h1, h2, b1, b2,
                                                  out12, N, N1);
}

// Round 20
// 181.726 us; speedup vs baseline: 1.1946x; 1.1332x over previous
//
#include <hip/hip_runtime.h>
#include <hip/hip_bf16.h>
#include <stdint.h>

#define D 128

typedef __attribute__((ext_vector_type(8))) short short8;
typedef __attribute__((ext_vector_type(4))) float f32x4;

__device__ inline unsigned short f2bf(float f) {
    union { float f; uint32_t u; } v; v.f = f;
    uint32_t u = v.u;
    uint32_t r = u + 0x7FFFu + ((u >> 16) & 1u);   // RNE
    return (unsigned short)(r >> 16);
}

__device__ inline float bf2f(uint32_t ubf) {
    union { uint32_t u; float f; } v; v.u = ubf << 16; return v.f;
}

// epilogue LDS swizzle
__device__ inline int eswz(int row) {
    return ((row & 3) << 5) | (((row >> 2) & 1) << 4);
}

// ---- fused: prep weights pre-swizzled (blocks 0..191) + zero cnt (blocks 192..)
__global__ void prep_zero(const float* __restrict__ W0, const float* __restrict__ W1,
                          const float* __restrict__ W2, unsigned short* __restrict__ Wt,
                          int* __restrict__ cnt, int nz) {
    int b = blockIdx.x;
    if (b < 192) {
        int idx = b * 256 + threadIdx.x;   // < 3*D*D = 49152
        int w = idx / (D * D);
        int rem = idx - w * D * D;
        int c = rem / D, k = rem - c * D;
        const float* W = (w == 0) ? W0 : ((w == 1) ? W1 : W2);
        int byte = ((c << 8) | (k << 1)) ^ ((c & 7) << 4);
        Wt[w * (D * D) + (byte >> 1)] = f2bf(W[k * D + c]);
    } else {
        int i = (b - 192) * 256 + threadIdx.x;
        if (i < nz) cnt[i] = 0;
    }
}

// ---- fused GEMM (+histogram-with-rank in trailing blocks)  [R15 shape]
__launch_bounds__(256, 3)
__global__ void gemm_hist(const float* __restrict__ x, const unsigned short* __restrict__ Wt,
                          const float* __restrict__ bln, float* __restrict__ out0,
                          unsigned short* __restrict__ h1, unsigned short* __restrict__ h2,
                          int N, int nGemm,
                          const int* __restrict__ ei1, const int* __restrict__ ei2,
                          int E1, int E2, int* __restrict__ cnt, int* __restrict__ epos,
                          int N1) {
    __shared__ char lA[64 * 256];    // epilogue bf16 staging (16KB)
    __shared__ char lB[D * 256];     // B stage, swizzled layout (32KB)
    const int b = blockIdx.x;
    const int tid = threadIdx.x;

    if (b >= nGemm) {                // histogram tail blocks: count + store rank
        int g = (b - nGemm) * 256 + tid;
        if (g < E1) {
            epos[g] = atomicAdd(&cnt[ei1[E1 + g]], 1);
        } else if (g < E1 + E2) {
            int e = g - E1;
            epos[g] = atomicAdd(&cnt[N1 + ei2[E2 + e]], 1);
        }
        return;
    }

    const int r0 = b * 64;
    const int wv = tid >> 6, lane = tid & 63;
    const int lr = lane & 15, lk = lane >> 4;

    // A fragments directly from global (f32 -> bf16 in regs)
    short8 afr[4];
    {
        int arow = r0 + wv * 16 + lr;
        if (arow < N) {
            const float* xr = x + (size_t)arow * D;
#pragma unroll
            for (int ks = 0; ks < 4; ++ks) {
                int c0 = ks * 32 + lk * 8;
                float4 va = *(const float4*)(xr + c0);
                float4 vb = *(const float4*)(xr + c0 + 4);
                short8 f;
                f[0] = (short)f2bf(va.x); f[1] = (short)f2bf(va.y);
                f[2] = (short)f2bf(va.z); f[3] = (short)f2bf(va.w);
                f[4] = (short)f2bf(vb.x); f[5] = (short)f2bf(vb.y);
                f[6] = (short)f2bf(vb.z); f[7] = (short)f2bf(vb.w);
                afr[ks] = f;
            }
        } else {
#pragma unroll
            for (int ks = 0; ks < 4; ++ks) afr[ks] = (short8)0;
        }
    }
    float blnv[8];
#pragma unroll
    for (int c = 0; c < 8; ++c) blnv[c] = bln[c * 16 + lr];

    for (int widx = 0; widx < 3; ++widx) {
        __syncthreads();   // prev iteration's lB MFMA reads + lA epilogue reads done
        // B tile: pre-swizzled global -> linear LDS (transient regs, 16B/thread x8)
        {
            const uint4* src = (const uint4*)(Wt + widx * D * D);
            uint4* dst = (uint4*)lB;
#pragma unroll
            for (int i = 0; i < 8; ++i) {
                int idx16 = i * 256 + tid;
                dst[idx16] = src[idx16];
            }
        }
        __syncthreads();

        f32x4 acc[8];
#pragma unroll
        for (int c = 0; c < 8; ++c) acc[c] = (f32x4)(0.f);

#pragma unroll
        for (int ks = 0; ks < 4; ++ks) {
            short8 bfr[8];
#pragma unroll
            for (int c = 0; c < 8; ++c) {
                int row = c * 16 + lr;
                int byte = row * 256 + ks * 64 + lk * 16;
                byte ^= (row & 7) << 4;
                bfr[c] = *(const short8*)(lB + byte);
            }
#pragma unroll
            for (int c = 0; c < 8; ++c)
                acc[c] = __builtin_amdgcn_mfma_f32_16x16x32_bf16(afr[ks], bfr[c], acc[c], 0, 0, 0);
        }

        // C/D mapping: col=lane&15, row=(lane>>4)*4+i
        if (widx == 0) {
            // i-outer/c-inner: one row's 8 col-chunks issue back-to-back
#pragma unroll
            for (int i = 0; i < 4; ++i) {
                int grow = r0 + wv * 16 + lk * 4 + i;
                if (grow < N) {
                    float* orow = out0 + (size_t)grow * D;
#pragma unroll
                    for (int c = 0; c < 8; ++c)
                        orow[c * 16 + lr] = acc[c][i] + blnv[c];
                }
            }
        } else {
#pragma unroll
            for (int c = 0; c < 8; ++c) {
                int col = c * 16 + lr;
#pragma unroll
                for (int i = 0; i < 4; ++i) {
                    int row_l = wv * 16 + lk * 4 + i;
                    int byt = (row_l * 256 + col * 2) ^ eswz(row_l);
                    *(unsigned short*)(lA + byt) = f2bf(acc[c][i]);
                }
            }
            __syncthreads();
            unsigned short* h = (widx == 1) ? h1 : h2;
#pragma unroll
            for (int i = 0; i < 4; ++i) {
                int idx = i * 256 + tid;
                int lin = idx * 16;
                int row_l = lin >> 8;
                int rb = lin ^ eswz(row_l);
                uint4 v = *(const uint4*)(lA + rb);
                int grow = r0 + row_l;
                if (grow < N)
                    *(uint4*)((char*)h + (size_t)grow * 256 + (lin & 255)) = v;
            }
        }
    }
}

// ---- exclusive scan, 1024 elems/block (256 thr x 4); block sums left un-added
__global__ void scan1_k(const int* __restrict__ cnt, int* __restrict__ excl,
                        int* __restrict__ bsum, int n) {
    __shared__ int s[256];
    int t = threadIdx.x;
    int base = blockIdx.x * 1024 + t * 4;
    int v0 = 0, v1 = 0, v2 = 0, v3 = 0;
    if (base + 3 < n) {
        int4 q = *(const int4*)(cnt + base);
        v0 = q.x; v1 = q.y; v2 = q.z; v3 = q.w;
    } else {
        if (base < n) v0 = cnt[base];
        if (base + 1 < n) v1 = cnt[base + 1];
        if (base + 2 < n) v2 = cnt[base + 2];
    }
    int sum = v0 + v1 + v2 + v3;
    s[t] = sum; __syncthreads();
    for (int off = 1; off < 256; off <<= 1) {
        int x = (t >= off) ? s[t - off] : 0;
        __syncthreads();
        s[t] += x;
        __syncthreads();
    }
    if (t == 255) bsum[blockIdx.x] = s[255];
    int run = s[t] - sum;
    if (base < n) excl[base] = run;
    if (base + 1 < n) excl[base + 1] = run + v0;
    if (base + 2 < n) excl[base + 2] = run + v0 + v1;
    if (base + 3 < n) excl[base + 3] = run + v0 + v1 + v2;
}

__global__ void scan2_k(int* __restrict__ bsum, int nb) {
    __shared__ int s[256];
    int t = threadIdx.x;
    int v = (t < nb) ? bsum[t] : 0;
    s[t] = v; __syncthreads();
    for (int off = 1; off < 256; off <<= 1) {
        int x = (t >= off) ? s[t - off] : 0;
        __syncthreads();
        s[t] += x;
        __syncthreads();
    }
    if (t < nb) bsum[t] = s[t] - v;
}

// ---- fill slots (no atomics): slot[rowptr[bin]+bsum[bin>>10]+epos[g]] = {src, w}
__global__ void fill_k(const int* __restrict__ ei1, const float* __restrict__ ew1,
                       const int* __restrict__ ei2, const float* __restrict__ ew2,
                       int E1, int E2, const int* __restrict__ rowptr,
                       const int* __restrict__ bsum, const int* __restrict__ epos,
                       uint2* __restrict__ slots, int N1) {
    int g = blockIdx.x * blockDim.x + threadIdx.x;
    int src, bin; float w;
    if (g < E1) {
        src = ei1[g]; bin = ei1[E1 + g]; w = ew1[g];
    } else if (g < E1 + E2) {
        int e = g - E1;
        src = ei2[e]; bin = N1 + ei2[E2 + e]; w = ew2[e];
    } else return;
    uint2 v; v.x = (unsigned)src; v.y = __float_as_uint(w);
    slots[rowptr[bin] + bsum[bin >> 10] + epos[g]] = v;
}

// ---- gather: one wave per (branch,node); quarter-wave edge pairing.
__launch_bounds__(256)
__global__ void gather_k(const uint2* __restrict__ slots, const int* __restrict__ rowptr,
                         const int* __restrict__ bsum,
                         const unsigned short* __restrict__ h1, const unsigned short* __restrict__ h2,
                         const float* __restrict__ b1, const float* __restrict__ b2,
                         float* __restrict__ out12, int N, int N1) {
    int wave = (blockIdx.x * 256 + threadIdx.x) >> 6;   // [0, 2N)
    int lane = threadIdx.x & 63;
    if (wave >= 2 * N) return;
    int q = lane >> 4, sl = lane & 15;
    int br = wave >= N;
    int node = wave - br * N;
    int rp = br * N1 + node;
    int beg = rowptr[rp] + bsum[rp >> 10];
    int end = rowptr[rp + 1] + bsum[(rp + 1) >> 10];
    const unsigned short* h = br ? h2 : h1;
    const float* bias = br ? b2 : b1;

    float a[8];
#pragma unroll
    for (int i = 0; i < 8; ++i) a[i] = 0.f;

    int j = beg + q;
    for (; j + 4 < end; j += 8) {
        uint2 s0 = slots[j], s1 = slots[j + 4];
        uint4 p0 = *(const uint4*)(h + (size_t)s0.x * D + sl * 8);
        uint4 p1 = *(const uint4*)(h + (size_t)s1.x * D + sl * 8);
        float w0 = __uint_as_float(s0.y), w1 = __uint_as_float(s1.y);
        a[0] += w0 * bf2f(p0.x & 0xFFFFu) + w1 * bf2f(p1.x & 0xFFFFu);
        a[1] += w0 * bf2f(p0.x >> 16)     + w1 * bf2f(p1.x >> 16);
        a[2] += w0 * bf2f(p0.y & 0xFFFFu) + w1 * bf2f(p1.y & 0xFFFFu);
        a[3] += w0 * bf2f(p0.y >> 16)     + w1 * bf2f(p1.y >> 16);
        a[4] += w0 * bf2f(p0.z & 0xFFFFu) + w1 * bf2f(p1.z & 0xFFFFu);
        a[5] += w0 * bf2f(p0.z >> 16)     + w1 * bf2f(p1.z >> 16);
        a[6] += w0 * bf2f(p0.w & 0xFFFFu) + w1 * bf2f(p1.w & 0xFFFFu);
        a[7] += w0 * bf2f(p0.w >> 16)     + w1 * bf2f(p1.w >> 16);
    }
    if (j < end) {
        uint2 s0 = slots[j];
        uint4 p0 = *(const uint4*)(h + (size_t)s0.x * D + sl * 8);
        float w0 = __uint_as_float(s0.y);
        a[0] += w0 * bf2f(p0.x & 0xFFFFu);
        a[1] += w0 * bf2f(p0.x >> 16);
        a[2] += w0 * bf2f(p0.y & 0xFFFFu);
        a[3] += w0 * bf2f(p0.y >> 16);
        a[4] += w0 * bf2f(p0.z & 0xFFFFu);
        a[5] += w0 * bf2f(p0.z >> 16);
        a[6] += w0 * bf2f(p0.w & 0xFFFFu);
        a[7] += w0 * bf2f(p0.w >> 16);
    }
#pragma unroll
    for (int i = 0; i < 8; ++i) {
        a[i] += __shfl_xor(a[i], 16);
        a[i] += __shfl_xor(a[i], 32);
    }
    if (q == 0) {
        float4 b0 = *(const float4*)(bias + sl * 8);
        float4 b1v = *(const float4*)(bias + sl * 8 + 4);
        f32x4 o0, o1;
        o0[0] = a[0] + b0.x;  o0[1] = a[1] + b0.y;  o0[2] = a[2] + b0.z;  o0[3] = a[3] + b0.w;
        o1[0] = a[4] + b1v.x; o1[1] = a[5] + b1v.y; o1[2] = a[6] + b1v.z; o1[3] = a[7] + b1v.w;
        float* dst = out12 + (size_t)wave * D + sl * 8;
        __builtin_nontemporal_store(o0, (f32x4*)dst);
        __builtin_nontemporal_store(o1, (f32x4*)(dst + 4));
    }
}

extern "C" void kernel_launch(void* const* d_in, const int* in_sizes, int n_in,
                              void* d_out, int out_size, void* d_ws, size_t ws_size,
                              hipStream_t stream) {
    const float* x   = (const float*)d_in[0];
    const int*   ei1 = (const int*)d_in[1];
    const float* ew1 = (const float*)d_in[2];
    const int*   ei2 = (const int*)d_in[3];
    const float* ew2 = (const float*)d_in[4];
    const float* Wln = (const float*)d_in[5];
    const float* bln = (const float*)d_in[6];
    const float* W1  = (const float*)d_in[7];
    const float* b1  = (const float*)d_in[8];
    const float* W2  = (const float*)d_in[9];
    const float* b2  = (const float*)d_in[10];

    const int N  = in_sizes[0] / D;
    const int E1 = in_sizes[2];
    const int E2 = in_sizes[4];
    const int N1 = N + 1;
    const int n  = 2 * N1;                 // concatenated bins
    const int nb = (n + 1023) / 1024;      // scan blocks (<=256)

    float* out0  = (float*)d_out;
    float* out12 = out0 + (size_t)N * D;

    char* ws = (char*)d_ws;
    size_t off = 0;
    auto alloc = [&](size_t bytes) { char* p = ws + off; off += (bytes + 63) & ~(size_t)63; return p; };
    unsigned short* h1     = (unsigned short*)alloc((size_t)N * D * 2);
    unsigned short* h2     = (unsigned short*)alloc((size_t)N * D * 2);
    unsigned short* Wt     = (unsigned short*)alloc(3 * D * D * 2);
    int*            cnt    = (int*)alloc((size_t)n * 4);
    int*            rowptr = (int*)alloc((size_t)n * 4);
    int*            bsum   = (int*)alloc(1024);
    int*            epos   = (int*)alloc((size_t)(E1 + E2) * 4);
    uint2*          slots  = (uint2*)alloc((size_t)(E1 + E2) * 8);

    const int nGemm = (N + 63) / 64;
    const int nHist = (E1 + E2 + 255) / 256;
    const int nZero = (n + 255) / 256;

    prep_zero<<<192 + nZero, 256, 0, stream>>>(Wln, W1, W2, Wt, cnt, n);
    gemm_hist<<<nGemm + nHist, 256, 0, stream>>>(x, Wt, bln, out0, h1, h2, N, nGemm,
                                                 ei1, ei2, E1, E2, cnt, epos, N1);
    scan1_k<<<nb, 256, 0, stream>>>(cnt, rowptr, bsum, n);
    scan2_k<<<1, 256, 0, stream>>>(bsum, nb);
    fill_k<<<(E1 + E2 + 255) / 256, 256, 0, stream>>>(ei1, ew1, ei2, ew2, E1, E2,
                                                      rowptr, bsum, epos, slots, N1);
    gather_k<<<(2 * N + 3) / 4, 256, 0, stream>>>(slots, rowptr, bsum, h1, h2, b1, b2,
                                                  out12, N, N1);
}